// Round 1
// baseline (129.041 us; speedup 1.0000x reference)
//
#include <hip/hip_runtime.h>

#define NM 8     // marginals
#define NN 128   // nodes
#define NI 127   // intervals

// Thomas-algorithm elimination multipliers for the fixed tridiagonal system
// (interior rows: sub=1, diag=4, sup=1; c[0]=c[127]=0). cp[i] = 1/(4-cp[i-1]).
struct CpTab { float v[NN]; };
constexpr CpTab make_cp() {
    CpTab t{};
    t.v[0] = 0.0f;
    double p = 0.0;
    for (int i = 1; i <= 126; ++i) { p = 1.0 / (4.0 - p); t.v[i] = (float)p; }
    t.v[127] = 0.0f;
    return t;
}
__constant__ CpTab CP = make_cp();

// Kernel 1: per-marginal natural cubic spline coefficients -> d_ws as float4(a,b,c,d)
// Also zeroes d_out (harness poisons it to 0xAA before every timed launch).
__global__ void spline_coeff_kernel(const float* __restrict__ nodal,
                                    float4* __restrict__ coef,
                                    float* __restrict__ out) {
    __shared__ float dp_s[NM][NN];
    __shared__ float c_s[NM][NN];
    int f = threadIdx.x;
    if (f == 0) out[0] = 0.0f;
    if (f >= NM) return;

    const float* y = nodal + f * NN;
    const float h     = 8.0f / 127.0f;
    const float inv_h = 127.0f / 8.0f;
    const float inv_h2 = inv_h * inv_h;

    // forward sweep: dp[i] = (rhs[i] - dp[i-1]) * cp[i]
    float prev = 0.0f;
    for (int i = 1; i <= 126; ++i) {
        float rhs = 3.0f * (y[i - 1] - 2.0f * y[i] + y[i + 1]) * inv_h2;
        prev = (rhs - prev) * CP.v[i];
        dp_s[f][i] = prev;
    }
    // back substitution: c[i] = dp[i] - cp[i]*c[i+1]
    float cn = 0.0f;
    c_s[f][127] = 0.0f;
    for (int i = 126; i >= 1; --i) {
        cn = dp_s[f][i] - CP.v[i] * cn;
        c_s[f][i] = cn;
    }
    c_s[f][0] = 0.0f;

    for (int i = 0; i < NI; ++i) {
        float ci  = c_s[f][i];
        float ci1 = c_s[f][i + 1];
        float a = y[i];
        float b = (y[i + 1] - y[i]) * inv_h - h * (2.0f * ci + ci1) * (1.0f / 3.0f);
        float d = (ci1 - ci) * inv_h * (1.0f / 3.0f);
        coef[f * NI + i] = make_float4(a, b, ci, d);
    }
}

__device__ __forceinline__ float eval1(float xv, const float4* __restrict__ cfr) {
    // match reference bucketization: clamp(ceil(((x+4)/8)*127)-1, 0, 126)
    float xs = (xv + 4.0f) * 0.125f;
    int idx = (int)ceilf(xs * 127.0f) - 1;
    idx = min(max(idx, 0), NI - 1);
    float node = fmaf((float)idx, 8.0f / 127.0f, -4.0f);
    float yv = xv - node;
    float4 cf = cfr[idx];
    return fmaf(yv, fmaf(yv, fmaf(yv, cf.w, cf.z), cf.y), cf.x);
}

// Kernel 2: evaluate + global sum. x is (bs=32, f=8, 256, 256) contiguous:
// 65536 elements (16384 float4) per (bs,f) slab -> f = (i4 >> 14) & 7.
__global__ __launch_bounds__(256)
void spline_eval_kernel(const float4* __restrict__ x,
                        const float4* __restrict__ coef,
                        float* __restrict__ out, int n4) {
    __shared__ float4 cf[NM * NI];   // 16256 B
    __shared__ float wsum[4];
    for (int t = threadIdx.x; t < NM * NI; t += 256) cf[t] = coef[t];
    __syncthreads();

    float acc = 0.0f;
    int gid = blockIdx.x * 256 + threadIdx.x;
    int gstride = gridDim.x * 256;
    for (int i = gid; i < n4; i += gstride) {
        float4 xv = x[i];
        const float4* cfr = cf + ((i >> 14) & 7) * NI;
        acc += eval1(xv.x, cfr);
        acc += eval1(xv.y, cfr);
        acc += eval1(xv.z, cfr);
        acc += eval1(xv.w, cfr);
    }

    // wave-64 reduce
    #pragma unroll
    for (int off = 32; off > 0; off >>= 1) acc += __shfl_down(acc, off);
    int lane = threadIdx.x & 63;
    int wid  = threadIdx.x >> 6;
    if (lane == 0) wsum[wid] = acc;
    __syncthreads();
    if (threadIdx.x == 0) {
        float s = wsum[0] + wsum[1] + wsum[2] + wsum[3];
        atomicAdd(out, s);
    }
}

extern "C" void kernel_launch(void* const* d_in, const int* in_sizes, int n_in,
                              void* d_out, int out_size, void* d_ws, size_t ws_size,
                              hipStream_t stream) {
    const float* x     = (const float*)d_in[0];
    const float* nodal = (const float*)d_in[1];
    float* out   = (float*)d_out;
    float4* coef = (float4*)d_ws;   // NM*NI*16 = 16256 bytes

    spline_coeff_kernel<<<1, 64, 0, stream>>>(nodal, coef, out);

    int n4 = in_sizes[0] / 4;       // 4194304
    spline_eval_kernel<<<2048, 256, 0, stream>>>((const float4*)x, coef, out, n4);
}

// Round 2
// 114.686 us; speedup vs baseline: 1.1252x; 1.1252x over previous
//
#include <hip/hip_runtime.h>

#define NM 8     // marginals
#define NN 128   // nodes
#define NI 127   // intervals
#define SPAD 129 // padded row stride for scratch (breaks 8-way f-conflict in sweeps)

// Thomas-algorithm elimination multipliers for the fixed interior [1,4,1] system
// (c[0]=c[127]=0). cp[i] = 1/(4 - cp[i-1]).
struct CpTab { float v[NN]; };
constexpr CpTab make_cp() {
    CpTab t{};
    t.v[0] = 0.0f;
    double p = 0.0;
    for (int i = 1; i <= 126; ++i) { p = 1.0 / (4.0 - p); t.v[i] = (float)p; }
    t.v[127] = 0.0f;
    return t;
}
__constant__ CpTab CP = make_cp();

__device__ __forceinline__ float eval1(float xv,
                                       const float2* __restrict__ tAB,
                                       const float2* __restrict__ tCD) {
    // reference bucketization: clamp(ceil(((x+4)/8)*127)-1, 0, 126)
    // (x+4)*0.125 is exact (pow2), so one mul by 15.875f is bit-identical.
    float t = xv + 4.0f;
    int idx = (int)ceilf(t * 15.875f) - 1;
    idx = min(max(idx, 0), NI - 1);
    float y = fmaf((float)idx, -(8.0f / 127.0f), t);   // y = (x+4) - idx*h
    float2 ab = tAB[idx];
    float2 cd = tCD[idx];
    return fmaf(y, fmaf(y, fmaf(y, cd.y, cd.x), ab.y), ab.x);
}

// Fused: per-block spline coefficient solve (redundant, tiny) + eval + global sum.
// x is (32, 8, 256, 256) contiguous: 16384 float4 per (bs,f) slab.
__global__ __launch_bounds__(256)
void spline_fused_kernel(const float4* __restrict__ x,
                         const float* __restrict__ nodal,
                         float* __restrict__ out, int n4) {
    __shared__ float  yv[NM * NN];       // 4096 B  nodal values
    __shared__ float  sc[NM * SPAD];     // 4128 B  rhs -> dp -> c (in place)
    __shared__ float2 tabAB[NM * NI];    // 8128 B  (a, b)
    __shared__ float2 tabCD[NM * NI];    // 8128 B  (c, d)
    __shared__ float  wsum[4];

    const int tid = threadIdx.x;
    const float h      = 8.0f / 127.0f;
    const float inv_h  = 127.0f / 8.0f;
    const float inv_h2 = inv_h * inv_h;

    // --- phase 1: load nodal, compute rhs in parallel ---
    for (int t = tid; t < NM * NN; t += 256) yv[t] = nodal[t];
    __syncthreads();
    for (int t = tid; t < NM * 126; t += 256) {
        int f = t / 126, i = t - f * 126 + 1;            // i in [1,126]
        float r = 3.0f * (yv[f * NN + i - 1] - 2.0f * yv[f * NN + i] + yv[f * NN + i + 1]) * inv_h2;
        sc[f * SPAD + i] = r;
    }
    __syncthreads();

    // --- phase 2: serial Thomas sweeps, one marginal per lane (wave 0 only) ---
    if (tid < NM) {
        const int f = tid;
        float prev = 0.0f;
        #pragma unroll
        for (int i = 1; i <= 126; ++i) {
            prev = (sc[f * SPAD + i] - prev) * CP.v[i];
            sc[f * SPAD + i] = prev;                     // dp in place
        }
        float cn = 0.0f;
        #pragma unroll
        for (int i = 126; i >= 1; --i) {
            cn = sc[f * SPAD + i] - CP.v[i] * cn;
            sc[f * SPAD + i] = cn;                       // c in place
        }
        sc[f * SPAD + 0]   = 0.0f;
        sc[f * SPAD + 127] = 0.0f;
    }
    __syncthreads();

    // --- phase 3: build (a,b) / (c,d) tables in parallel ---
    for (int t = tid; t < NM * NI; t += 256) {
        int f = t / NI, i = t - f * NI;
        float ci  = sc[f * SPAD + i];
        float ci1 = sc[f * SPAD + i + 1];
        float a = yv[f * NN + i];
        float b = (yv[f * NN + i + 1] - a) * inv_h - h * (2.0f * ci + ci1) * (1.0f / 3.0f);
        float d = (ci1 - ci) * inv_h * (1.0f / 3.0f);
        tabAB[t] = make_float2(a, b);
        tabCD[t] = make_float2(ci, d);
    }
    __syncthreads();

    // --- phase 4: evaluate + sum. 16 float4 per thread, batches of 4 for MLP ---
    const int gid = blockIdx.x * 256 + tid;
    const int S   = gridDim.x * 256;                     // f4 stride between batch items
    // marginal index is invariant across k*S steps (S/16384 is a multiple of 8)
    const int f = (gid >> 14) & 7;
    const float2* __restrict__ tAB = tabAB + f * NI;
    const float2* __restrict__ tCD = tabCD + f * NI;

    float acc = 0.0f;
    for (int b = 0; b < 4; ++b) {
        int i0 = gid + (b * 4) * S;
        if (i0 + 3 * S < n4) {
            float4 v0 = x[i0];
            float4 v1 = x[i0 + S];
            float4 v2 = x[i0 + 2 * S];
            float4 v3 = x[i0 + 3 * S];
            acc += eval1(v0.x, tAB, tCD); acc += eval1(v0.y, tAB, tCD);
            acc += eval1(v0.z, tAB, tCD); acc += eval1(v0.w, tAB, tCD);
            acc += eval1(v1.x, tAB, tCD); acc += eval1(v1.y, tAB, tCD);
            acc += eval1(v1.z, tAB, tCD); acc += eval1(v1.w, tAB, tCD);
            acc += eval1(v2.x, tAB, tCD); acc += eval1(v2.y, tAB, tCD);
            acc += eval1(v2.z, tAB, tCD); acc += eval1(v2.w, tAB, tCD);
            acc += eval1(v3.x, tAB, tCD); acc += eval1(v3.y, tAB, tCD);
            acc += eval1(v3.z, tAB, tCD); acc += eval1(v3.w, tAB, tCD);
        } else {
            for (int u = 0; u < 4; ++u) {
                int i = i0 + u * S;
                if (i < n4) {
                    float4 v = x[i];
                    acc += eval1(v.x, tAB, tCD); acc += eval1(v.y, tAB, tCD);
                    acc += eval1(v.z, tAB, tCD); acc += eval1(v.w, tAB, tCD);
                }
            }
        }
    }

    // --- reduction: wave-64 shuffle -> LDS -> one atomic per block ---
    #pragma unroll
    for (int off = 32; off > 0; off >>= 1) acc += __shfl_down(acc, off);
    int lane = tid & 63;
    int wid  = tid >> 6;
    if (lane == 0) wsum[wid] = acc;
    __syncthreads();
    if (tid == 0) {
        atomicAdd(out, wsum[0] + wsum[1] + wsum[2] + wsum[3]);
    }
}

extern "C" void kernel_launch(void* const* d_in, const int* in_sizes, int n_in,
                              void* d_out, int out_size, void* d_ws, size_t ws_size,
                              hipStream_t stream) {
    const float* x     = (const float*)d_in[0];
    const float* nodal = (const float*)d_in[1];
    float* out = (float*)d_out;

    hipMemsetAsync(out, 0, sizeof(float) * out_size, stream);

    int n4 = in_sizes[0] / 4;                  // 4,194,304
    int elems_per_thread_f4 = 16;
    int grid = (n4 + 256 * elems_per_thread_f4 - 1) / (256 * elems_per_thread_f4);  // 1024
    spline_fused_kernel<<<grid, 256, 0, stream>>>((const float4*)x, nodal, out, n4);
}

// Round 3
// 114.545 us; speedup vs baseline: 1.1266x; 1.0012x over previous
//
#include <hip/hip_runtime.h>

#define NM 8     // marginals
#define NN 128   // nodes
#define NI 127   // intervals
#define SPAD 129 // padded row stride for scratch

#define GRID 2048
#define PT 8     // float4 per thread, all loaded up-front for MLP

// Thomas-algorithm elimination multipliers for the fixed interior [1,4,1] system.
struct CpTab { float v[NN]; };
constexpr CpTab make_cp() {
    CpTab t{};
    t.v[0] = 0.0f;
    double p = 0.0;
    for (int i = 1; i <= 126; ++i) { p = 1.0 / (4.0 - p); t.v[i] = (float)p; }
    t.v[127] = 0.0f;
    return t;
}
__constant__ CpTab CP = make_cp();

__device__ __forceinline__ float eval1(float xv,
                                       const float2* __restrict__ tAB,
                                       const float2* __restrict__ tCD) {
    // reference bucketization: clamp(ceil(((x+4)/8)*127)-1, 0, 126)
    float t = xv + 4.0f;
    int idx = (int)ceilf(t * 15.875f) - 1;
    idx = min(max(idx, 0), NI - 1);
    float y = fmaf((float)idx, -(8.0f / 127.0f), t);   // y = (x+4) - idx*h
    float2 ab = tAB[idx];
    float2 cd = tCD[idx];
    return fmaf(y, fmaf(y, fmaf(y, cd.y, cd.x), ab.y), ab.x);
}

// Fused: per-block coefficient solve (redundant, tiny) + eval; per-block
// partial sums go to d_ws (plain store -> no output-zeroing memset needed).
__global__ __launch_bounds__(256)
void spline_fused_kernel(const float4* __restrict__ x,
                         const float* __restrict__ nodal,
                         float* __restrict__ partials, int n4) {
    __shared__ float  yv[NM * NN];       // 4096 B
    __shared__ float  sc[NM * SPAD];     // 4128 B
    __shared__ float2 tabAB[NM * NI];    // 8128 B
    __shared__ float2 tabCD[NM * NI];    // 8128 B
    __shared__ float  wsum[4];

    const int tid = threadIdx.x;
    const float h      = 8.0f / 127.0f;
    const float inv_h  = 127.0f / 8.0f;
    const float inv_h2 = inv_h * inv_h;

    // phase 1: nodal -> LDS, rhs in parallel
    for (int t = tid; t < NM * NN; t += 256) yv[t] = nodal[t];
    __syncthreads();
    for (int t = tid; t < NM * 126; t += 256) {
        int f = t / 126, i = t - f * 126 + 1;
        sc[f * SPAD + i] = 3.0f * (yv[f * NN + i - 1] - 2.0f * yv[f * NN + i]
                                   + yv[f * NN + i + 1]) * inv_h2;
    }
    __syncthreads();

    // phase 2: serial Thomas sweeps, one marginal per lane (wave 0)
    if (tid < NM) {
        const int f = tid;
        float prev = 0.0f;
        #pragma unroll
        for (int i = 1; i <= 126; ++i) {
            prev = (sc[f * SPAD + i] - prev) * CP.v[i];
            sc[f * SPAD + i] = prev;
        }
        float cn = 0.0f;
        #pragma unroll
        for (int i = 126; i >= 1; --i) {
            cn = sc[f * SPAD + i] - CP.v[i] * cn;
            sc[f * SPAD + i] = cn;
        }
        sc[f * SPAD + 0]   = 0.0f;
        sc[f * SPAD + 127] = 0.0f;
    }
    __syncthreads();

    // phase 3: build (a,b)/(c,d) tables
    for (int t = tid; t < NM * NI; t += 256) {
        int f = t / NI, i = t - f * NI;
        float ci  = sc[f * SPAD + i];
        float ci1 = sc[f * SPAD + i + 1];
        float a = yv[f * NN + i];
        float b = (yv[f * NN + i + 1] - a) * inv_h - h * (2.0f * ci + ci1) * (1.0f / 3.0f);
        float d = (ci1 - ci) * inv_h * (1.0f / 3.0f);
        tabAB[t] = make_float2(a, b);
        tabCD[t] = make_float2(ci, d);
    }
    __syncthreads();

    // phase 4: ALL PT loads issued up-front (MLP), then evaluate.
    const int gid = blockIdx.x * 256 + tid;
    const int S   = GRID * 256;              // stride; S/16384 multiple of 8 -> f invariant
    const int f = (gid >> 14) & 7;
    const float2* __restrict__ tAB = tabAB + f * NI;
    const float2* __restrict__ tCD = tabCD + f * NI;

    float acc = 0.0f;
    if (gid + (PT - 1) * S < n4) {
        float4 v[PT];
        #pragma unroll
        for (int k = 0; k < PT; ++k) v[k] = x[gid + k * S];
        #pragma unroll
        for (int k = 0; k < PT; ++k) {
            acc += eval1(v[k].x, tAB, tCD);
            acc += eval1(v[k].y, tAB, tCD);
            acc += eval1(v[k].z, tAB, tCD);
            acc += eval1(v[k].w, tAB, tCD);
        }
    } else {
        for (int k = 0; k < PT; ++k) {
            int i = gid + k * S;
            if (i < n4) {
                float4 v = x[i];
                acc += eval1(v.x, tAB, tCD); acc += eval1(v.y, tAB, tCD);
                acc += eval1(v.z, tAB, tCD); acc += eval1(v.w, tAB, tCD);
            }
        }
    }

    // wave-64 reduce -> LDS -> plain store of block partial
    #pragma unroll
    for (int off = 32; off > 0; off >>= 1) acc += __shfl_down(acc, off);
    int lane = tid & 63;
    int wid  = tid >> 6;
    if (lane == 0) wsum[wid] = acc;
    __syncthreads();
    if (tid == 0) partials[blockIdx.x] = wsum[0] + wsum[1] + wsum[2] + wsum[3];
}

// 1 block: sum GRID partials, plain store (out needs no pre-zeroing).
__global__ __launch_bounds__(256)
void final_reduce_kernel(const float* __restrict__ partials, float* __restrict__ out) {
    __shared__ float wsum[4];
    float a = 0.0f;
    for (int i = threadIdx.x; i < GRID; i += 256) a += partials[i];
    #pragma unroll
    for (int off = 32; off > 0; off >>= 1) a += __shfl_down(a, off);
    int lane = threadIdx.x & 63, wid = threadIdx.x >> 6;
    if (lane == 0) wsum[wid] = a;
    __syncthreads();
    if (threadIdx.x == 0) out[0] = wsum[0] + wsum[1] + wsum[2] + wsum[3];
}

extern "C" void kernel_launch(void* const* d_in, const int* in_sizes, int n_in,
                              void* d_out, int out_size, void* d_ws, size_t ws_size,
                              hipStream_t stream) {
    const float* x     = (const float*)d_in[0];
    const float* nodal = (const float*)d_in[1];
    float* out      = (float*)d_out;
    float* partials = (float*)d_ws;

    int n4 = in_sizes[0] / 4;   // 4,194,304 = GRID*256*PT exactly
    spline_fused_kernel<<<GRID, 256, 0, stream>>>((const float4*)x, nodal, partials, n4);
    final_reduce_kernel<<<1, 256, 0, stream>>>(partials, out);
}

// Round 4
// 108.091 us; speedup vs baseline: 1.1938x; 1.0597x over previous
//
#include <hip/hip_runtime.h>

#define NM 8     // marginals
#define NN 128   // nodes
#define NI 127   // intervals
#define SPAD 129 // padded row stride for solve scratch

#define GRID 2048
#define PT 8     // float4 per thread, all loaded up-front for MLP

// Thomas-algorithm elimination multipliers for the fixed interior [1,4,1] system.
struct CpTab { float v[NN]; };
constexpr CpTab make_cp() {
    CpTab t{};
    t.v[0] = 0.0f;
    double p = 0.0;
    for (int i = 1; i <= 126; ++i) { p = 1.0 / (4.0 - p); t.v[i] = (float)p; }
    t.v[127] = 0.0f;
    return t;
}
__constant__ CpTab CP = make_cp();

// ---------- Kernel A: coefficient solve, ONCE (1 block). Writes split tables. ----------
__global__ __launch_bounds__(256)
void spline_coeff_kernel(const float* __restrict__ nodal,
                         float2* __restrict__ gAB,
                         float2* __restrict__ gCD) {
    __shared__ float yv[NM * NN];
    __shared__ float sc[NM * SPAD];
    const int tid = threadIdx.x;
    const float h      = 8.0f / 127.0f;
    const float inv_h  = 127.0f / 8.0f;
    const float inv_h2 = inv_h * inv_h;

    for (int t = tid; t < NM * NN; t += 256) yv[t] = nodal[t];
    __syncthreads();
    for (int t = tid; t < NM * 126; t += 256) {
        int f = t / 126, i = t - f * 126 + 1;
        sc[f * SPAD + i] = 3.0f * (yv[f * NN + i - 1] - 2.0f * yv[f * NN + i]
                                   + yv[f * NN + i + 1]) * inv_h2;
    }
    __syncthreads();
    if (tid < NM) {               // serial Thomas sweeps, one marginal per lane
        const int f = tid;
        float prev = 0.0f;
        #pragma unroll
        for (int i = 1; i <= 126; ++i) {
            prev = (sc[f * SPAD + i] - prev) * CP.v[i];
            sc[f * SPAD + i] = prev;
        }
        float cn = 0.0f;
        #pragma unroll
        for (int i = 126; i >= 1; --i) {
            cn = sc[f * SPAD + i] - CP.v[i] * cn;
            sc[f * SPAD + i] = cn;
        }
        sc[f * SPAD + 0]   = 0.0f;
        sc[f * SPAD + 127] = 0.0f;
    }
    __syncthreads();
    for (int t = tid; t < NM * NI; t += 256) {
        int f = t / NI, i = t - f * NI;
        float ci  = sc[f * SPAD + i];
        float ci1 = sc[f * SPAD + i + 1];
        float a = yv[f * NN + i];
        float b = (yv[f * NN + i + 1] - a) * inv_h - h * (2.0f * ci + ci1) * (1.0f / 3.0f);
        float d = (ci1 - ci) * inv_h * (1.0f / 3.0f);
        gAB[t] = make_float2(a, b);
        gCD[t] = make_float2(ci, d);
    }
}

__device__ __forceinline__ float eval1(float xv,
                                       const float2* __restrict__ tAB,
                                       const float2* __restrict__ tCD) {
    // reference bucketization: clamp(ceil(((x+4)/8)*127)-1, 0, 126)
    float t = xv + 4.0f;
    int idx = (int)ceilf(t * 15.875f) - 1;
    idx = min(max(idx, 0), NI - 1);
    float y = fmaf((float)idx, -(8.0f / 127.0f), t);   // y = (x+4) - idx*h
    float2 ab = tAB[idx];
    float2 cd = tCD[idx];
    return fmaf(y, fmaf(y, fmaf(y, cd.y, cd.x), ab.y), ab.x);
}

// ---------- Kernel B: eval + per-block partials. Trivial preamble. ----------
__global__ __launch_bounds__(256)
void spline_eval_kernel(const float4* __restrict__ x,
                        const float4* __restrict__ gAB4,   // NM*NI float2 = 508 float4
                        const float4* __restrict__ gCD4,
                        float* __restrict__ partials, int n4) {
    __shared__ float2 tabAB[NM * NI];    // 8128 B
    __shared__ float2 tabCD[NM * NI];    // 8128 B
    __shared__ float  wsum[4];
    const int tid = threadIdx.x;

    // coalesced 16 KB table load (L2/L3-resident after block 0)
    for (int t = tid; t < 508; t += 256) {
        ((float4*)tabAB)[t] = gAB4[t];
        ((float4*)tabCD)[t] = gCD4[t];
    }
    __syncthreads();

    const int gid = blockIdx.x * 256 + tid;
    const int S   = GRID * 256;          // stride; S/16384 multiple of 8 -> f invariant
    const int f = (gid >> 14) & 7;
    const float2* __restrict__ tAB = tabAB + f * NI;
    const float2* __restrict__ tCD = tabCD + f * NI;

    float acc = 0.0f;
    if (gid + (PT - 1) * S < n4) {
        float4 v[PT];
        #pragma unroll
        for (int k = 0; k < PT; ++k) v[k] = x[gid + k * S];   // all 8 loads in flight
        #pragma unroll
        for (int k = 0; k < PT; ++k) {
            acc += eval1(v[k].x, tAB, tCD);
            acc += eval1(v[k].y, tAB, tCD);
            acc += eval1(v[k].z, tAB, tCD);
            acc += eval1(v[k].w, tAB, tCD);
        }
    } else {
        for (int k = 0; k < PT; ++k) {
            int i = gid + k * S;
            if (i < n4) {
                float4 v = x[i];
                acc += eval1(v.x, tAB, tCD); acc += eval1(v.y, tAB, tCD);
                acc += eval1(v.z, tAB, tCD); acc += eval1(v.w, tAB, tCD);
            }
        }
    }

    #pragma unroll
    for (int off = 32; off > 0; off >>= 1) acc += __shfl_down(acc, off);
    int lane = tid & 63;
    int wid  = tid >> 6;
    if (lane == 0) wsum[wid] = acc;
    __syncthreads();
    if (tid == 0) partials[blockIdx.x] = wsum[0] + wsum[1] + wsum[2] + wsum[3];
}

// ---------- Kernel C: final reduce (plain store; no pre-zero needed). ----------
__global__ __launch_bounds__(256)
void final_reduce_kernel(const float* __restrict__ partials, float* __restrict__ out) {
    __shared__ float wsum[4];
    float a = 0.0f;
    for (int i = threadIdx.x; i < GRID; i += 256) a += partials[i];
    #pragma unroll
    for (int off = 32; off > 0; off >>= 1) a += __shfl_down(a, off);
    int lane = threadIdx.x & 63, wid = threadIdx.x >> 6;
    if (lane == 0) wsum[wid] = a;
    __syncthreads();
    if (threadIdx.x == 0) out[0] = wsum[0] + wsum[1] + wsum[2] + wsum[3];
}

extern "C" void kernel_launch(void* const* d_in, const int* in_sizes, int n_in,
                              void* d_out, int out_size, void* d_ws, size_t ws_size,
                              hipStream_t stream) {
    const float* x     = (const float*)d_in[0];
    const float* nodal = (const float*)d_in[1];
    float* out = (float*)d_out;

    // d_ws layout: [0, 8128)   tabAB (float2[1016])
    //              [8192,16320) tabCD
    //              [16384, +8KB) partials (float[2048])
    char* ws = (char*)d_ws;
    float2* gAB     = (float2*)(ws);
    float2* gCD     = (float2*)(ws + 8192);
    float* partials = (float*)(ws + 16384);

    int n4 = in_sizes[0] / 4;   // 4,194,304 = GRID*256*PT exactly

    spline_coeff_kernel<<<1, 256, 0, stream>>>(nodal, gAB, gCD);
    spline_eval_kernel<<<GRID, 256, 0, stream>>>((const float4*)x,
                                                 (const float4*)gAB, (const float4*)gCD,
                                                 partials, n4);
    final_reduce_kernel<<<1, 256, 0, stream>>>(partials, out);
}